// Round 10
// baseline (234.229 us; speedup 1.0000x reference)
//
#include <hip/hip_runtime.h>
#include <hip/hip_bf16.h>
#include <math.h>

// N = 100000, E = 3.2M, F_in = 128, H = C = 16. int inputs arrive as int32.
//
// out[d] = dinv[d]*(sum_{s->d} u[s] + u[d]) + b,  u = dinv .* (h @ W).
// R3/R20: global per-edge atomics unusable. R21: LDS f32 atomicAdd gather
//     303us (CAS semantics) dead. R19 coop fusion dead.
// R18 = 221.8us best of CSR pipeline (R16 8n/wave + R17 uint4 + R18 xw1).
// R22 = 222.7us: fixed-capacity binning (binR+sortcsr replaces 4-kernel
//     exact-prefix chain). NEUTRAL total but exposed binR = 46us with
//     WRITE_SIZE 55-65MB vs 12.8MB payload (4-5x write amp).
// R23: per-XCD sub-regions. Amp mechanism: bucket sub-ranges are filled in
//     reservation order -> 64B lines shared by blocks on DIFFERENT XCDs ->
//     dirty-line migration between non-coherent per-XCD L2s + frontier
//     evictions. Fix: bucket region (8192) split into 8 sub-regions (1024 =
//     mean 512 + 22sig) keyed by xcd = blockIdx.x & 7. All writes to a
//     sub-region come from one XCD. sortcsr reads 8 sub-runs per bucket.

#define F_IN 128
#define H 16
#define NPB 128            // nodes per bucket
#define MAX_NB 800         // max buckets (N <= 102400)
#define NBLK 256           // binning blocks (edge-range partition)
#define BINT 1024          // binning threads per block
#define CAPB 13            // log2 bucket capacity (8192)
#define SUBB 10            // log2 per-XCD sub-capacity (1024)
#define SMAX 4864          // LDS sort clamp (mean 4096, +12 sigma)
#define PFD 3              // prefetch depth: 16 slots * 3 = 48 edges/node
#define NPW 8              // nodes per wave
#define NPBLK 32           // nodes per block = 4 waves * NPW

typedef __hip_bfloat16 bf16;

__device__ __forceinline__ float bflo(unsigned v) { return __uint_as_float(v << 16); }
__device__ __forceinline__ float bfhi(unsigned v) { return __uint_as_float(v & 0xffff0000u); }

// XCD round-robin: adjacent logical edge-ranges land on the same XCD
__device__ __forceinline__ int swz(int p) { return (p & 7) * 32 + (p >> 3); }

// ---- prep 0: cursor[b*8+x] = 0 (offsets within per-XCD sub-regions) ----
__global__ void init_kernel(int* __restrict__ cursor, int n) {
    for (int i = threadIdx.x; i < n; i += 1024) cursor[i] = 0;
}

// ---- prep 1: hist + per-XCD reserve + scatter; packed=(dst&127)<<17|src ----
__global__ void binR_kernel(const int* __restrict__ src, const int* __restrict__ dst,
                            int* __restrict__ cursor, unsigned* __restrict__ packed,
                            int E, int NB) {
    __shared__ int h[MAX_NB];
    int b = swz(blockIdx.x);
    int xcd = blockIdx.x & 7;              // physical round-robin XCD id
    long long e0 = (long long)E * b / NBLK;
    long long e1 = (long long)E * (b + 1) / NBLK;
    for (int i = threadIdx.x; i < NB; i += BINT) h[i] = 0;
    __syncthreads();
    for (long long e = e0 + threadIdx.x; e < e1; e += BINT)
        atomicAdd(&h[dst[e] >> 7], 1);
    __syncthreads();
    // reserve this block's chunk inside its XCD's sub-region of each bucket
    for (int i = threadIdx.x; i < NB; i += BINT) {
        int c = h[i];
        int off = (c > 0) ? atomicAdd(&cursor[i * 8 + xcd], c) : 0;
        h[i] = (i << CAPB) + (xcd << SUBB) + off;
    }
    __syncthreads();
    for (long long e = e0 + threadIdx.x; e < e1; e += BINT) {
        int d = dst[e];
        int bk = d >> 7;
        int p = atomicAdd(&h[bk], 1);
        if (p < (bk << CAPB) + ((xcd + 1) << SUBB))    // sub-region bound
            packed[p] = (unsigned)src[e] | ((unsigned)(d & 127) << 17);
    }
}

// ---- prep 2: per-bucket LDS counting sort over 8 sub-runs ----
__global__ void sortcsr_kernel(const unsigned* __restrict__ packed, const int* __restrict__ cursor,
                               unsigned* __restrict__ sorted, int2* __restrict__ rowpair,
                               float* __restrict__ dinv, int N) {
    __shared__ unsigned ssort[SMAX];
    __shared__ int cnt[NPB], offs[NPB], cur[NPB];
    __shared__ int rlen[8];
    int b = blockIdx.x;
    int rbase = b << CAPB;
    int T = blockDim.x;

    if (threadIdx.x < 8) {
        int l = cursor[b * 8 + threadIdx.x];
        rlen[threadIdx.x] = (l > (1 << SUBB)) ? (1 << SUBB) : l;
    }
    for (int i = threadIdx.x; i < NPB; i += T) cnt[i] = 0;
    __syncthreads();

    int totlen = 0;
#pragma unroll
    for (int x = 0; x < 8; x++) {
        int rl = rlen[x];
        const unsigned* rp = packed + rbase + (x << SUBB);
        for (int i = threadIdx.x; i < rl; i += T)
            atomicAdd(&cnt[rp[i] >> 17], 1);
        totlen += rl;
    }
    if (totlen > SMAX) totlen = SMAX;
    __syncthreads();
    if (threadIdx.x < NPB) offs[threadIdx.x] = cnt[threadIdx.x];
    __syncthreads();
    for (int off = 1; off < NPB; off <<= 1) {
        int v = 0;
        if (threadIdx.x < NPB && threadIdx.x >= off) v = offs[threadIdx.x - off];
        __syncthreads();
        if (threadIdx.x < NPB) offs[threadIdx.x] += v;
        __syncthreads();
    }
    if (threadIdx.x < NPB) {
        int ex = offs[threadIdx.x] - cnt[threadIdx.x];
        cur[threadIdx.x] = ex;
        int node = b * NPB + threadIdx.x;
        if (node < N) {
            rowpair[node] = make_int2(rbase + ex, rbase + ex + cnt[threadIdx.x]);
            dinv[node] = rsqrtf(1.0f + (float)cnt[threadIdx.x]);
        }
    }
    __syncthreads();
#pragma unroll
    for (int x = 0; x < 8; x++) {
        int rl = rlen[x];
        const unsigned* rp = packed + rbase + (x << SUBB);
        for (int i = threadIdx.x; i < rl; i += T) {
            unsigned p = rp[i];
            int pos = atomicAdd(&cur[p >> 17], 1);
            if (pos < SMAX) ssort[pos] = p;
        }
    }
    __syncthreads();
    for (int i = threadIdx.x; i < totlen; i += T) sorted[rbase + i] = ssort[i];
}

// ---- u[i][j] = dinv[i] * sum_k x[i][k]*W1[k][j]  (bf16 out) ----
// R18: 4 outputs per thread. lane = (row r: tid>>2) x (jq: tid&3 -> 4 ch).
#define XR 64
#define XPAD 132
__global__ void xw1_kernel(const float* __restrict__ x, const float* __restrict__ W1,
                           const float* __restrict__ dinv, bf16* __restrict__ u, int n) {
    __shared__ float sW1[F_IN * H];        // 8 KB, [k*16 + j]
    __shared__ float sx[XR * XPAD];        // 33.8 KB
    for (int t = threadIdx.x; t < F_IN * H; t += 256) sW1[t] = W1[t];

    int basei = blockIdx.x * XR;
    for (int idx = threadIdx.x; idx < XR * 32; idx += 256) {
        int r = idx >> 5;                  // 0..63
        int kk = (idx & 31) << 2;          // 0,4,...,124
        int row = basei + r;
        float4 v = make_float4(0.f, 0.f, 0.f, 0.f);
        if (row < n) v = *(const float4*)(x + (size_t)row * F_IN + kk);
        *(float4*)(sx + r * XPAD + kk) = v;
    }
    __syncthreads();

    int r = threadIdx.x >> 2;              // 0..63
    int jq = (threadIdx.x & 3) << 2;       // 0,4,8,12
    int row = basei + r;
    if (row >= n) return;

    const float* xr = sx + r * XPAD;
    float a0 = 0.f, a1 = 0.f, a2 = 0.f, a3 = 0.f;
#pragma unroll 16
    for (int k = 0; k < F_IN; k++) {
        float xk = xr[k];
        float4 w = *(const float4*)(sW1 + k * H + jq);
        a0 += xk * w.x; a1 += xk * w.y; a2 += xk * w.z; a3 += xk * w.w;
    }
    float di = dinv[row];
    bf16 b0 = __float2bfloat16(di * a0);
    bf16 b1 = __float2bfloat16(di * a1);
    bf16 b2 = __float2bfloat16(di * a2);
    bf16 b3 = __float2bfloat16(di * a3);
    ushort4 pk = make_ushort4(*(unsigned short*)&b0, *(unsigned short*)&b1,
                              *(unsigned short*)&b2, *(unsigned short*)&b3);
    *(ushort4*)((unsigned short*)u + (size_t)row * H + jq) = pk;
}

// ================= pipelined gather core (shared by both layers) =============
// R17 lane layout: b0 = j8 (channel octet: 8 bf16 = uint4 = 16B),
// b1 = p (node parity: 2 nodes per wave-iteration), b2..b5 = g (slot 0..15).
// Depth-2 pipeline (R13 shape): prefetch sorted for pair t+1 while consuming
// uv for pair t; uv for t+1 issued after the consume.
#define GATHER_TILE(UVPTR)                                                      \
    int lane = threadIdx.x & 63;                                                \
    int wave = threadIdx.x >> 6;                                                \
    int j8 = lane & 1, pp = (lane >> 1) & 1, g = lane >> 2;                     \
    int nodeBase = blockIdx.x * NPBLK + wave * NPW;                             \
    int r0c = 0, r1c = 0;                                                       \
    unsigned svc[PFD]; uint4 uvc[PFD];                                          \
    {   int node = nodeBase + pp;                                               \
        if (node < N) { int2 rp = rowpair[node]; r0c = rp.x; r1c = rp.y; }      \
        _Pragma("unroll")                                                       \
        for (int m = 0; m < PFD; m++) {                                         \
            int k = r0c + g + 16 * m;                                           \
            if (k < r1c) svc[m] = sorted[k];                                    \
        }                                                                       \
        _Pragma("unroll")                                                       \
        for (int m = 0; m < PFD; m++) {                                         \
            int k = r0c + g + 16 * m;                                           \
            if (k < r1c) uvc[m] = UVPTR[(size_t)(svc[m] & 0x1FFFF) * 2 + j8];   \
        }                                                                       \
    }                                                                           \
    for (int t = 0; t < NPW / 2; t++) {                                         \
        int r0n = 0, r1n = 0;                                                   \
        unsigned svn[PFD];                                                      \
        if (t < NPW / 2 - 1) {                                                  \
            int nn = nodeBase + 2 * (t + 1) + pp;                               \
            if (nn < N) { int2 rp = rowpair[nn]; r0n = rp.x; r1n = rp.y; }      \
            _Pragma("unroll")                                                   \
            for (int m = 0; m < PFD; m++) {                                     \
                int k = r0n + g + 16 * m;                                       \
                if (k < r1n) svn[m] = sorted[k];                                \
            }                                                                   \
        }                                                                       \
        float a0=0.f,a1=0.f,a2=0.f,a3=0.f,a4=0.f,a5=0.f,a6=0.f,a7=0.f;          \
        _Pragma("unroll")                                                       \
        for (int m = 0; m < PFD; m++) {                                         \
            int k = r0c + g + 16 * m;                                           \
            if (k < r1c) {                                                      \
                a0 += bflo(uvc[m].x); a1 += bfhi(uvc[m].x);                     \
                a2 += bflo(uvc[m].y); a3 += bfhi(uvc[m].y);                     \
                a4 += bflo(uvc[m].z); a5 += bfhi(uvc[m].z);                     \
                a6 += bflo(uvc[m].w); a7 += bfhi(uvc[m].w);                     \
            }                                                                   \
        }                                                                       \
        for (int k = r0c + g + 16 * PFD; k < r1c; k += 16) {                    \
            uint4 va = UVPTR[(size_t)(sorted[k] & 0x1FFFF) * 2 + j8];           \
            a0 += bflo(va.x); a1 += bfhi(va.x);                                 \
            a2 += bflo(va.y); a3 += bfhi(va.y);                                 \
            a4 += bflo(va.z); a5 += bfhi(va.z);                                 \
            a6 += bflo(va.w); a7 += bfhi(va.w);                                 \
        }                                                                       \
        _Pragma("unroll")                                                       \
        for (int off = 4; off <= 32; off <<= 1) {                               \
            a0 += __shfl_xor(a0, off); a1 += __shfl_xor(a1, off);               \
            a2 += __shfl_xor(a2, off); a3 += __shfl_xor(a3, off);               \
            a4 += __shfl_xor(a4, off); a5 += __shfl_xor(a5, off);               \
            a6 += __shfl_xor(a6, off); a7 += __shfl_xor(a7, off);               \
        }                                                                       \
        if (g == 0) {                                                           \
            float* tp = &tile[(wave * NPW + 2 * t + pp) * 16 + 8 * j8];         \
            tp[0]=a0; tp[1]=a1; tp[2]=a2; tp[3]=a3;                             \
            tp[4]=a4; tp[5]=a5; tp[6]=a6; tp[7]=a7;                             \
        }                                                                       \
        if (t < NPW / 2 - 1) {                                                  \
            r0c = r0n; r1c = r1n;                                               \
            _Pragma("unroll")                                                   \
            for (int m = 0; m < PFD; m++) {                                     \
                int k = r0n + g + 16 * m;                                       \
                svc[m] = svn[m];                                                \
                if (k < r1n) uvc[m] = UVPTR[(size_t)(svn[m] & 0x1FFFF) * 2 + j8]; \
            }                                                                   \
        }                                                                       \
    }

// ---- layer-1 gather + finalize ----
__global__ void gatherfin1_kernel(const unsigned* __restrict__ sorted, const int2* __restrict__ rowpair,
                                  const bf16* __restrict__ u, const float* __restrict__ dinv,
                                  const float* __restrict__ b1, const float* __restrict__ W2,
                                  bf16* __restrict__ u2, int N) {
    __shared__ float tile[NPBLK * 16];
    __shared__ float sW2[256];
    __shared__ float sb1[16];
    sW2[threadIdx.x] = W2[threadIdx.x];
    if (threadIdx.x < 16) sb1[threadIdx.x] = b1[threadIdx.x];

    const uint4* uvp = (const uint4*)u;   // [node*2 + j8] channel octets
    GATHER_TILE(uvp)
    __syncthreads();

    int jj = threadIdx.x & 15;
    for (int rr = 0; rr < NPBLK / 16; rr++) {
        int rl = (threadIdx.x >> 4) + rr * 16;
        int node = blockIdx.x * NPBLK + rl;
        float h = 0.f, di = 0.f;
        if (node < N) {
            di = dinv[node];
            h = di * (tile[rl * 16 + jj] + __bfloat162float(u[(size_t)node * H + jj])) + sb1[jj];
            h = fmaxf(h, 0.f);
        }
        float acc2 = 0.f;
#pragma unroll
        for (int kk = 0; kk < 16; kk++) {
            float hk = __shfl(h, kk, 16);
            acc2 += hk * sW2[kk * 16 + jj];
        }
        if (node < N) u2[(size_t)node * H + jj] = __float2bfloat16(di * acc2);
    }
}

// ---- layer-2 gather + finalize: log_softmax -> out (f32) ----
__global__ void gatherfin2_kernel(const unsigned* __restrict__ sorted, const int2* __restrict__ rowpair,
                                  const bf16* __restrict__ u2, const float* __restrict__ dinv,
                                  const float* __restrict__ b2, float* __restrict__ out, int N) {
    __shared__ float tile[NPBLK * 16];
    __shared__ float sb2[16];
    if (threadIdx.x < 16) sb2[threadIdx.x] = b2[threadIdx.x];

    const uint4* uvp = (const uint4*)u2;
    GATHER_TILE(uvp)
    __syncthreads();

    int jj = threadIdx.x & 15;
    for (int rr = 0; rr < NPBLK / 16; rr++) {
        int rl = (threadIdx.x >> 4) + rr * 16;
        int node = blockIdx.x * NPBLK + rl;
        if (node >= N) continue;
        float di = dinv[node];
        float v = di * (tile[rl * 16 + jj] + __bfloat162float(u2[(size_t)node * H + jj])) + sb2[jj];

        float m = v;
#pragma unroll
        for (int off = 8; off >= 1; off >>= 1) m = fmaxf(m, __shfl_xor(m, off, 16));
        float ex = __expf(v - m);
        float s = ex;
#pragma unroll
        for (int off = 8; off >= 1; off >>= 1) s += __shfl_xor(s, off, 16);

        out[(size_t)node * H + jj] = v - m - __logf(s);
    }
}

extern "C" void kernel_launch(void* const* d_in, const int* in_sizes, int n_in,
                              void* d_out, int out_size, void* d_ws, size_t ws_size,
                              hipStream_t stream) {
    const float* x = (const float*)d_in[0];
    const int* edge_index = (const int*)d_in[1];
    const float* W1 = (const float*)d_in[2];
    const float* b1 = (const float*)d_in[3];
    const float* W2 = (const float*)d_in[4];
    const float* b2 = (const float*)d_in[5];
    float* out = (float*)d_out;

    const int N = in_sizes[0] / F_IN;        // 100000
    const int E = in_sizes[1] / 2;           // 3200000
    const int* src = edge_index;
    const int* dst = edge_index + E;
    const int NB = (N + NPB - 1) / NPB;      // 782

    // ws (4B units): dinv[N] | u[N*H/2] | u2[N*H/2] | packed[NB<<CAPB] |
    //                sorted[NB<<CAPB] | cursor[MAX_NB*8] | rowpair[2N]
    float* dinv = (float*)d_ws;
    bf16* u = (bf16*)(dinv + N);
    bf16* u2 = (bf16*)((unsigned*)u + (size_t)N * H / 2);
    unsigned* packed = (unsigned*)((unsigned*)u2 + (size_t)N * H / 2);
    unsigned* sorted = packed + ((size_t)MAX_NB << CAPB);
    int* cursor = (int*)(sorted + ((size_t)MAX_NB << CAPB));
    int2* rowpair = (int2*)(cursor + MAX_NB * 8);

    init_kernel<<<1, 1024, 0, stream>>>(cursor, NB * 8);
    binR_kernel<<<NBLK, BINT, 0, stream>>>(src, dst, cursor, packed, E, NB);
    sortcsr_kernel<<<NB, 512, 0, stream>>>(packed, cursor, sorted, rowpair, dinv, N);

    xw1_kernel<<<(N + XR - 1) / XR, 256, 0, stream>>>(x, W1, dinv, u, N);
    gatherfin1_kernel<<<(N + NPBLK - 1) / NPBLK, 256, 0, stream>>>(sorted, rowpair, u, dinv, b1, W2, u2, N);
    gatherfin2_kernel<<<(N + NPBLK - 1) / NPBLK, 256, 0, stream>>>(sorted, rowpair, u2, dinv, b2, out, N);
}

// Round 11
// 221.807 us; speedup vs baseline: 1.0560x; 1.0560x over previous
//
#include <hip/hip_runtime.h>
#include <hip/hip_bf16.h>
#include <math.h>

// N = 100000, E = 3.2M, F_in = 128, H = C = 16. int inputs arrive as int32.
//
// out[d] = dinv[d]*(sum_{s->d} u[s] + u[d]) + b,  u = dinv .* (h @ W).
// R3/R20: global per-edge atomics unusable. R21: LDS f32 atomicAdd gather
//     dead (CAS semantics). R19 coop fusion dead. R23 per-XCD sub-regions
//     REGRESSED (write-amp UP: more partial-line frontiers, not fewer).
// R18 = 221.8us / R22 = 222.7us (fixed-cap binning, 3-kernel chain).
// binR diagnosis (R22/R23 counters): scatter stores are 64 random 4B txns
//     per wave store (random buckets) -> txn-rate bound + 4-7x write amp.
// R24: block-local LDS multisplit inside binR. After hist: exclusive scan
//     over buckets -> place block's 12.5K edges into LDS sorted-by-bucket
//     (ssort 50KB) -> write out PER-BUCKET RUNS (wave w handles buckets
//     w, w+16, ...; lanes write consecutive addresses). Mean run 16 edges
//     = 64B = full line: ~200K contiguous run-writes instead of 3.2M
//     scattered 4B. sortcsr/gathers/xw1 = R22 exactly.

#define F_IN 128
#define H 16
#define NPB 128            // nodes per bucket
#define MAX_NB 800         // max buckets (N <= 102400)
#define NBLK 256           // binning blocks (edge-range partition)
#define BINT 1024          // binning threads per block
#define CAPB 13            // log2 bucket capacity (8192)
#define LDSE 12544         // LDS edge buffer (>= ceil(E/NBLK) = 12500)
#define SMAX 4864          // LDS sort clamp (mean 4096, +12 sigma)
#define PFD 3              // prefetch depth: 16 slots * 3 = 48 edges/node
#define NPW 8              // nodes per wave
#define NPBLK 32           // nodes per block = 4 waves * NPW

typedef __hip_bfloat16 bf16;

__device__ __forceinline__ float bflo(unsigned v) { return __uint_as_float(v << 16); }
__device__ __forceinline__ float bfhi(unsigned v) { return __uint_as_float(v & 0xffff0000u); }

// XCD round-robin: adjacent logical edge-ranges land on the same XCD
__device__ __forceinline__ int swz(int p) { return (p & 7) * 32 + (p >> 3); }

// ---- prep 0: cursor[b] = b<<CAPB ----
__global__ void init_kernel(int* __restrict__ cursor, int NB) {
    int i = threadIdx.x;
    if (i < NB) cursor[i] = i << CAPB;
}

// ---- prep 1: hist + reserve + LDS multisplit + run-coalesced writeout ----
// packed value = (dst&127)<<17 | src
__global__ void __launch_bounds__(BINT)
binR_kernel(const int* __restrict__ src, const int* __restrict__ dst,
            int* __restrict__ cursor, unsigned* __restrict__ packed,
            int E, int NB) {
    __shared__ unsigned ssort[LDSE];       // 50.2 KB: block edges, bucket-sorted
    __shared__ int h[MAX_NB];              // hist -> placement cursor
    __shared__ int ls[1025];               // exclusive scan (ls[NB] = len)
    __shared__ int gb[MAX_NB];             // global reserved base per bucket
    int b = swz(blockIdx.x);
    long long e0 = (long long)E * b / NBLK;
    long long e1 = (long long)E * (b + 1) / NBLK;
    int len = (int)(e1 - e0);
    int t = threadIdx.x;

    for (int i = t; i < NB; i += BINT) h[i] = 0;
    __syncthreads();
    for (long long e = e0 + t; e < e1; e += BINT)
        atomicAdd(&h[dst[e] >> 7], 1);
    __syncthreads();

    // reserve global run + block-local exclusive scan
    int hv = (t < NB) ? h[t] : 0;
    if (t < NB) gb[t] = atomicAdd(&cursor[t], hv);
    ls[t] = hv;
    __syncthreads();
    for (int off = 1; off < 1024; off <<= 1) {
        int w = (t >= off) ? ls[t - off] : 0;
        __syncthreads();
        ls[t] += w;
        __syncthreads();
    }
    int excl = ls[t] - hv;
    __syncthreads();
    ls[t] = excl;
    if (t == 1023) ls[1024] = excl + hv;   // only used if NB==1024 (never)
    __syncthreads();

    if (len <= LDSE) {
        // placement cursors = local run starts
        if (t < NB) h[t] = ls[t];
        __syncthreads();
        for (long long e = e0 + t; e < e1; e += BINT) {
            int d = dst[e];
            int bk = d >> 7;
            int p = atomicAdd(&h[bk], 1);
            ssort[p] = (unsigned)src[e] | ((unsigned)(d & 127) << 17);
        }
        __syncthreads();
        // writeout: wave w copies bucket runs w, w+16, ... (coalesced runs)
        int wave = t >> 6, lane = t & 63;
        for (int bk = wave; bk < NB; bk += BINT / 64) {
            int s0 = ls[bk];
            int s1 = ls[bk + 1];
            int g0 = gb[bk];
            for (int i = s0 + lane; i < s1; i += 64)
                packed[g0 + (i - s0)] = ssort[i];
        }
    } else {
        // fallback (never hit for E=3.2M): direct scatter as R22
        if (t < NB) h[t] = gb[t];
        __syncthreads();
        for (long long e = e0 + t; e < e1; e += BINT) {
            int d = dst[e];
            int bk = d >> 7;
            int p = atomicAdd(&h[bk], 1);
            if (p < ((bk + 1) << CAPB))
                packed[p] = (unsigned)src[e] | ((unsigned)(d & 127) << 17);
        }
    }
}

// ---- prep 2: per-bucket LDS counting sort -> sorted[], rowpair[], dinv[] ----
__global__ void sortcsr_kernel(const unsigned* __restrict__ packed, const int* __restrict__ cursor,
                               unsigned* __restrict__ sorted, int2* __restrict__ rowpair,
                               float* __restrict__ dinv, int N) {
    __shared__ unsigned ssort[SMAX];
    __shared__ int cnt[NPB], offs[NPB], cur[NPB];
    int b = blockIdx.x;
    int e0 = b << CAPB;
    int len = cursor[b] - e0;
    if (len > SMAX) len = SMAX;
    int T = blockDim.x;

    for (int i = threadIdx.x; i < NPB; i += T) cnt[i] = 0;
    __syncthreads();
    for (int i = threadIdx.x; i < len; i += T)
        atomicAdd(&cnt[packed[e0 + i] >> 17], 1);
    __syncthreads();
    if (threadIdx.x < NPB) offs[threadIdx.x] = cnt[threadIdx.x];
    __syncthreads();
    for (int off = 1; off < NPB; off <<= 1) {
        int v = 0;
        if (threadIdx.x < NPB && threadIdx.x >= off) v = offs[threadIdx.x - off];
        __syncthreads();
        if (threadIdx.x < NPB) offs[threadIdx.x] += v;
        __syncthreads();
    }
    if (threadIdx.x < NPB) {
        int ex = offs[threadIdx.x] - cnt[threadIdx.x];
        cur[threadIdx.x] = ex;
        int node = b * NPB + threadIdx.x;
        if (node < N) {
            rowpair[node] = make_int2(e0 + ex, e0 + ex + cnt[threadIdx.x]);
            dinv[node] = rsqrtf(1.0f + (float)cnt[threadIdx.x]);
        }
    }
    __syncthreads();
    for (int i = threadIdx.x; i < len; i += T) {
        unsigned p = packed[e0 + i];
        int pos = atomicAdd(&cur[p >> 17], 1);
        ssort[pos] = p;
    }
    __syncthreads();
    for (int i = threadIdx.x; i < len; i += T) sorted[e0 + i] = ssort[i];
}

// ---- u[i][j] = dinv[i] * sum_k x[i][k]*W1[k][j]  (bf16 out) ----
// R18: 4 outputs per thread. lane = (row r: tid>>2) x (jq: tid&3 -> 4 ch).
#define XR 64
#define XPAD 132
__global__ void xw1_kernel(const float* __restrict__ x, const float* __restrict__ W1,
                           const float* __restrict__ dinv, bf16* __restrict__ u, int n) {
    __shared__ float sW1[F_IN * H];        // 8 KB, [k*16 + j]
    __shared__ float sx[XR * XPAD];        // 33.8 KB
    for (int t = threadIdx.x; t < F_IN * H; t += 256) sW1[t] = W1[t];

    int basei = blockIdx.x * XR;
    for (int idx = threadIdx.x; idx < XR * 32; idx += 256) {
        int r = idx >> 5;                  // 0..63
        int kk = (idx & 31) << 2;          // 0,4,...,124
        int row = basei + r;
        float4 v = make_float4(0.f, 0.f, 0.f, 0.f);
        if (row < n) v = *(const float4*)(x + (size_t)row * F_IN + kk);
        *(float4*)(sx + r * XPAD + kk) = v;
    }
    __syncthreads();

    int r = threadIdx.x >> 2;              // 0..63
    int jq = (threadIdx.x & 3) << 2;       // 0,4,8,12
    int row = basei + r;
    if (row >= n) return;

    const float* xr = sx + r * XPAD;
    float a0 = 0.f, a1 = 0.f, a2 = 0.f, a3 = 0.f;
#pragma unroll 16
    for (int k = 0; k < F_IN; k++) {
        float xk = xr[k];
        float4 w = *(const float4*)(sW1 + k * H + jq);
        a0 += xk * w.x; a1 += xk * w.y; a2 += xk * w.z; a3 += xk * w.w;
    }
    float di = dinv[row];
    bf16 b0 = __float2bfloat16(di * a0);
    bf16 b1 = __float2bfloat16(di * a1);
    bf16 b2 = __float2bfloat16(di * a2);
    bf16 b3 = __float2bfloat16(di * a3);
    ushort4 pk = make_ushort4(*(unsigned short*)&b0, *(unsigned short*)&b1,
                              *(unsigned short*)&b2, *(unsigned short*)&b3);
    *(ushort4*)((unsigned short*)u + (size_t)row * H + jq) = pk;
}

// ================= pipelined gather core (shared by both layers) =============
// R17 lane layout: b0 = j8 (channel octet: 8 bf16 = uint4 = 16B),
// b1 = p (node parity: 2 nodes per wave-iteration), b2..b5 = g (slot 0..15).
// Depth-2 pipeline (R13 shape): prefetch sorted for pair t+1 while consuming
// uv for pair t; uv for t+1 issued after the consume.
#define GATHER_TILE(UVPTR)                                                      \
    int lane = threadIdx.x & 63;                                                \
    int wave = threadIdx.x >> 6;                                                \
    int j8 = lane & 1, pp = (lane >> 1) & 1, g = lane >> 2;                     \
    int nodeBase = blockIdx.x * NPBLK + wave * NPW;                             \
    int r0c = 0, r1c = 0;                                                       \
    unsigned svc[PFD]; uint4 uvc[PFD];                                          \
    {   int node = nodeBase + pp;                                               \
        if (node < N) { int2 rp = rowpair[node]; r0c = rp.x; r1c = rp.y; }      \
        _Pragma("unroll")                                                       \
        for (int m = 0; m < PFD; m++) {                                         \
            int k = r0c + g + 16 * m;                                           \
            if (k < r1c) svc[m] = sorted[k];                                    \
        }                                                                       \
        _Pragma("unroll")                                                       \
        for (int m = 0; m < PFD; m++) {                                         \
            int k = r0c + g + 16 * m;                                           \
            if (k < r1c) uvc[m] = UVPTR[(size_t)(svc[m] & 0x1FFFF) * 2 + j8];   \
        }                                                                       \
    }                                                                           \
    for (int t = 0; t < NPW / 2; t++) {                                         \
        int r0n = 0, r1n = 0;                                                   \
        unsigned svn[PFD];                                                      \
        if (t < NPW / 2 - 1) {                                                  \
            int nn = nodeBase + 2 * (t + 1) + pp;                               \
            if (nn < N) { int2 rp = rowpair[nn]; r0n = rp.x; r1n = rp.y; }      \
            _Pragma("unroll")                                                   \
            for (int m = 0; m < PFD; m++) {                                     \
                int k = r0n + g + 16 * m;                                       \
                if (k < r1n) svn[m] = sorted[k];                                \
            }                                                                   \
        }                                                                       \
        float a0=0.f,a1=0.f,a2=0.f,a3=0.f,a4=0.f,a5=0.f,a6=0.f,a7=0.f;          \
        _Pragma("unroll")                                                       \
        for (int m = 0; m < PFD; m++) {                                         \
            int k = r0c + g + 16 * m;                                           \
            if (k < r1c) {                                                      \
                a0 += bflo(uvc[m].x); a1 += bfhi(uvc[m].x);                     \
                a2 += bflo(uvc[m].y); a3 += bfhi(uvc[m].y);                     \
                a4 += bflo(uvc[m].z); a5 += bfhi(uvc[m].z);                     \
                a6 += bflo(uvc[m].w); a7 += bfhi(uvc[m].w);                     \
            }                                                                   \
        }                                                                       \
        for (int k = r0c + g + 16 * PFD; k < r1c; k += 16) {                    \
            uint4 va = UVPTR[(size_t)(sorted[k] & 0x1FFFF) * 2 + j8];           \
            a0 += bflo(va.x); a1 += bfhi(va.x);                                 \
            a2 += bflo(va.y); a3 += bfhi(va.y);                                 \
            a4 += bflo(va.z); a5 += bfhi(va.z);                                 \
            a6 += bflo(va.w); a7 += bfhi(va.w);                                 \
        }                                                                       \
        _Pragma("unroll")                                                       \
        for (int off = 4; off <= 32; off <<= 1) {                               \
            a0 += __shfl_xor(a0, off); a1 += __shfl_xor(a1, off);               \
            a2 += __shfl_xor(a2, off); a3 += __shfl_xor(a3, off);               \
            a4 += __shfl_xor(a4, off); a5 += __shfl_xor(a5, off);               \
            a6 += __shfl_xor(a6, off); a7 += __shfl_xor(a7, off);               \
        }                                                                       \
        if (g == 0) {                                                           \
            float* tp = &tile[(wave * NPW + 2 * t + pp) * 16 + 8 * j8];         \
            tp[0]=a0; tp[1]=a1; tp[2]=a2; tp[3]=a3;                             \
            tp[4]=a4; tp[5]=a5; tp[6]=a6; tp[7]=a7;                             \
        }                                                                       \
        if (t < NPW / 2 - 1) {                                                  \
            r0c = r0n; r1c = r1n;                                               \
            _Pragma("unroll")                                                   \
            for (int m = 0; m < PFD; m++) {                                     \
                int k = r0n + g + 16 * m;                                       \
                svc[m] = svn[m];                                                \
                if (k < r1n) uvc[m] = UVPTR[(size_t)(svn[m] & 0x1FFFF) * 2 + j8]; \
            }                                                                   \
        }                                                                       \
    }

// ---- layer-1 gather + finalize ----
__global__ void gatherfin1_kernel(const unsigned* __restrict__ sorted, const int2* __restrict__ rowpair,
                                  const bf16* __restrict__ u, const float* __restrict__ dinv,
                                  const float* __restrict__ b1, const float* __restrict__ W2,
                                  bf16* __restrict__ u2, int N) {
    __shared__ float tile[NPBLK * 16];
    __shared__ float sW2[256];
    __shared__ float sb1[16];
    sW2[threadIdx.x] = W2[threadIdx.x];
    if (threadIdx.x < 16) sb1[threadIdx.x] = b1[threadIdx.x];

    const uint4* uvp = (const uint4*)u;   // [node*2 + j8] channel octets
    GATHER_TILE(uvp)
    __syncthreads();

    int jj = threadIdx.x & 15;
    for (int rr = 0; rr < NPBLK / 16; rr++) {
        int rl = (threadIdx.x >> 4) + rr * 16;
        int node = blockIdx.x * NPBLK + rl;
        float h = 0.f, di = 0.f;
        if (node < N) {
            di = dinv[node];
            h = di * (tile[rl * 16 + jj] + __bfloat162float(u[(size_t)node * H + jj])) + sb1[jj];
            h = fmaxf(h, 0.f);
        }
        float acc2 = 0.f;
#pragma unroll
        for (int kk = 0; kk < 16; kk++) {
            float hk = __shfl(h, kk, 16);
            acc2 += hk * sW2[kk * 16 + jj];
        }
        if (node < N) u2[(size_t)node * H + jj] = __float2bfloat16(di * acc2);
    }
}

// ---- layer-2 gather + finalize: log_softmax -> out (f32) ----
__global__ void gatherfin2_kernel(const unsigned* __restrict__ sorted, const int2* __restrict__ rowpair,
                                  const bf16* __restrict__ u2, const float* __restrict__ dinv,
                                  const float* __restrict__ b2, float* __restrict__ out, int N) {
    __shared__ float tile[NPBLK * 16];
    __shared__ float sb2[16];
    if (threadIdx.x < 16) sb2[threadIdx.x] = b2[threadIdx.x];

    const uint4* uvp = (const uint4*)u2;
    GATHER_TILE(uvp)
    __syncthreads();

    int jj = threadIdx.x & 15;
    for (int rr = 0; rr < NPBLK / 16; rr++) {
        int rl = (threadIdx.x >> 4) + rr * 16;
        int node = blockIdx.x * NPBLK + rl;
        if (node >= N) continue;
        float di = dinv[node];
        float v = di * (tile[rl * 16 + jj] + __bfloat162float(u2[(size_t)node * H + jj])) + sb2[jj];

        float m = v;
#pragma unroll
        for (int off = 8; off >= 1; off >>= 1) m = fmaxf(m, __shfl_xor(m, off, 16));
        float ex = __expf(v - m);
        float s = ex;
#pragma unroll
        for (int off = 8; off >= 1; off >>= 1) s += __shfl_xor(s, off, 16);

        out[(size_t)node * H + jj] = v - m - __logf(s);
    }
}

extern "C" void kernel_launch(void* const* d_in, const int* in_sizes, int n_in,
                              void* d_out, int out_size, void* d_ws, size_t ws_size,
                              hipStream_t stream) {
    const float* x = (const float*)d_in[0];
    const int* edge_index = (const int*)d_in[1];
    const float* W1 = (const float*)d_in[2];
    const float* b1 = (const float*)d_in[3];
    const float* W2 = (const float*)d_in[4];
    const float* b2 = (const float*)d_in[5];
    float* out = (float*)d_out;

    const int N = in_sizes[0] / F_IN;        // 100000
    const int E = in_sizes[1] / 2;           // 3200000
    const int* src = edge_index;
    const int* dst = edge_index + E;
    const int NB = (N + NPB - 1) / NPB;      // 782

    // ws (4B units): dinv[N] | u[N*H/2] | u2[N*H/2] | packed[NB<<CAPB] |
    //                sorted[NB<<CAPB] | cursor[MAX_NB] | rowpair[2N]
    float* dinv = (float*)d_ws;
    bf16* u = (bf16*)(dinv + N);
    bf16* u2 = (bf16*)((unsigned*)u + (size_t)N * H / 2);
    unsigned* packed = (unsigned*)((unsigned*)u2 + (size_t)N * H / 2);
    unsigned* sorted = packed + ((size_t)MAX_NB << CAPB);
    int* cursor = (int*)(sorted + ((size_t)MAX_NB << CAPB));
    int2* rowpair = (int2*)(cursor + MAX_NB);

    init_kernel<<<1, 1024, 0, stream>>>(cursor, NB);
    binR_kernel<<<NBLK, BINT, 0, stream>>>(src, dst, cursor, packed, E, NB);
    sortcsr_kernel<<<NB, 512, 0, stream>>>(packed, cursor, sorted, rowpair, dinv, N);

    xw1_kernel<<<(N + XR - 1) / XR, 256, 0, stream>>>(x, W1, dinv, u, N);
    gatherfin1_kernel<<<(N + NPBLK - 1) / NPBLK, 256, 0, stream>>>(sorted, rowpair, u, dinv, b1, W2, u2, N);
    gatherfin2_kernel<<<(N + NPBLK - 1) / NPBLK, 256, 0, stream>>>(sorted, rowpair, u2, dinv, b2, out, N);
}

// Round 12
// 218.705 us; speedup vs baseline: 1.0710x; 1.0142x over previous
//
#include <hip/hip_runtime.h>
#include <hip/hip_bf16.h>
#include <math.h>

// N = 100000, E = 3.2M, F_in = 128, H = C = 16. int inputs arrive as int32.
//
// out[d] = dinv[d]*(sum_{s->d} u[s] + u[d]) + b,  u = dinv .* (h @ W).
// R3/R20: global per-edge atomics unusable. R21: LDS f32 atomicAdd gather
//     dead (CAS semantics). R19 coop fusion dead. R23 per-XCD sub-regions
//     regressed (write-amp UP).
// R18 = 221.8us. R22 = 222.7 (fixed-cap binning). R24 = 221.8: binR LDS
//     multisplit + run-coalesced writeout fixed the 4-7x scatter write-amp
//     (binR 46 -> <39, out of top-5). Budget: ~80us harness fills (2x262MB,
//     untouchable) + binR ~30 + sortcsr ~20 + xw1 ~9 + gathers ~72 + gaps.
// R25: gathers are the largest controllable block (latency-bound, ~37us
//     each vs ~13us L2-txn floor). NPW 8 -> 4 (R16's proven lever, next
//     rung): 25K waves (~98/CU, 3x oversub) for deeper latency hiding +
//     finer tail granularity. Everything else identical to R24.

#define F_IN 128
#define H 16
#define NPB 128            // nodes per bucket
#define MAX_NB 800         // max buckets (N <= 102400)
#define NBLK 256           // binning blocks (edge-range partition)
#define BINT 1024          // binning threads per block
#define CAPB 13            // log2 bucket capacity (8192)
#define LDSE 12544         // LDS edge buffer (>= ceil(E/NBLK) = 12500)
#define SMAX 4864          // LDS sort clamp (mean 4096, +12 sigma)
#define PFD 3              // prefetch depth: 16 slots * 3 = 48 edges/node
#define NPW 4              // nodes per wave (R25: was 8)
#define NPBLK 16           // nodes per block = 4 waves * NPW

typedef __hip_bfloat16 bf16;

__device__ __forceinline__ float bflo(unsigned v) { return __uint_as_float(v << 16); }
__device__ __forceinline__ float bfhi(unsigned v) { return __uint_as_float(v & 0xffff0000u); }

// XCD round-robin: adjacent logical edge-ranges land on the same XCD
__device__ __forceinline__ int swz(int p) { return (p & 7) * 32 + (p >> 3); }

// ---- prep 0: cursor[b] = b<<CAPB ----
__global__ void init_kernel(int* __restrict__ cursor, int NB) {
    int i = threadIdx.x;
    if (i < NB) cursor[i] = i << CAPB;
}

// ---- prep 1: hist + reserve + LDS multisplit + run-coalesced writeout ----
// packed value = (dst&127)<<17 | src
__global__ void __launch_bounds__(BINT)
binR_kernel(const int* __restrict__ src, const int* __restrict__ dst,
            int* __restrict__ cursor, unsigned* __restrict__ packed,
            int E, int NB) {
    __shared__ unsigned ssort[LDSE];       // 50.2 KB: block edges, bucket-sorted
    __shared__ int h[MAX_NB];              // hist -> placement cursor
    __shared__ int ls[1025];               // exclusive scan (ls[NB] = len)
    __shared__ int gb[MAX_NB];             // global reserved base per bucket
    int b = swz(blockIdx.x);
    long long e0 = (long long)E * b / NBLK;
    long long e1 = (long long)E * (b + 1) / NBLK;
    int len = (int)(e1 - e0);
    int t = threadIdx.x;

    for (int i = t; i < NB; i += BINT) h[i] = 0;
    __syncthreads();
    for (long long e = e0 + t; e < e1; e += BINT)
        atomicAdd(&h[dst[e] >> 7], 1);
    __syncthreads();

    // reserve global run + block-local exclusive scan
    int hv = (t < NB) ? h[t] : 0;
    if (t < NB) gb[t] = atomicAdd(&cursor[t], hv);
    ls[t] = hv;
    __syncthreads();
    for (int off = 1; off < 1024; off <<= 1) {
        int w = (t >= off) ? ls[t - off] : 0;
        __syncthreads();
        ls[t] += w;
        __syncthreads();
    }
    int excl = ls[t] - hv;
    __syncthreads();
    ls[t] = excl;
    if (t == 1023) ls[1024] = excl + hv;   // only used if NB==1024 (never)
    __syncthreads();

    if (len <= LDSE) {
        // placement cursors = local run starts
        if (t < NB) h[t] = ls[t];
        __syncthreads();
        for (long long e = e0 + t; e < e1; e += BINT) {
            int d = dst[e];
            int bk = d >> 7;
            int p = atomicAdd(&h[bk], 1);
            ssort[p] = (unsigned)src[e] | ((unsigned)(d & 127) << 17);
        }
        __syncthreads();
        // writeout: wave w copies bucket runs w, w+16, ... (coalesced runs)
        int wave = t >> 6, lane = t & 63;
        for (int bk = wave; bk < NB; bk += BINT / 64) {
            int s0 = ls[bk];
            int s1 = ls[bk + 1];
            int g0 = gb[bk];
            for (int i = s0 + lane; i < s1; i += 64)
                packed[g0 + (i - s0)] = ssort[i];
        }
    } else {
        // fallback (never hit for E=3.2M): direct scatter as R22
        if (t < NB) h[t] = gb[t];
        __syncthreads();
        for (long long e = e0 + t; e < e1; e += BINT) {
            int d = dst[e];
            int bk = d >> 7;
            int p = atomicAdd(&h[bk], 1);
            if (p < ((bk + 1) << CAPB))
                packed[p] = (unsigned)src[e] | ((unsigned)(d & 127) << 17);
        }
    }
}

// ---- prep 2: per-bucket LDS counting sort -> sorted[], rowpair[], dinv[] ----
__global__ void sortcsr_kernel(const unsigned* __restrict__ packed, const int* __restrict__ cursor,
                               unsigned* __restrict__ sorted, int2* __restrict__ rowpair,
                               float* __restrict__ dinv, int N) {
    __shared__ unsigned ssort[SMAX];
    __shared__ int cnt[NPB], offs[NPB], cur[NPB];
    int b = blockIdx.x;
    int e0 = b << CAPB;
    int len = cursor[b] - e0;
    if (len > SMAX) len = SMAX;
    int T = blockDim.x;

    for (int i = threadIdx.x; i < NPB; i += T) cnt[i] = 0;
    __syncthreads();
    for (int i = threadIdx.x; i < len; i += T)
        atomicAdd(&cnt[packed[e0 + i] >> 17], 1);
    __syncthreads();
    if (threadIdx.x < NPB) offs[threadIdx.x] = cnt[threadIdx.x];
    __syncthreads();
    for (int off = 1; off < NPB; off <<= 1) {
        int v = 0;
        if (threadIdx.x < NPB && threadIdx.x >= off) v = offs[threadIdx.x - off];
        __syncthreads();
        if (threadIdx.x < NPB) offs[threadIdx.x] += v;
        __syncthreads();
    }
    if (threadIdx.x < NPB) {
        int ex = offs[threadIdx.x] - cnt[threadIdx.x];
        cur[threadIdx.x] = ex;
        int node = b * NPB + threadIdx.x;
        if (node < N) {
            rowpair[node] = make_int2(e0 + ex, e0 + ex + cnt[threadIdx.x]);
            dinv[node] = rsqrtf(1.0f + (float)cnt[threadIdx.x]);
        }
    }
    __syncthreads();
    for (int i = threadIdx.x; i < len; i += T) {
        unsigned p = packed[e0 + i];
        int pos = atomicAdd(&cur[p >> 17], 1);
        ssort[pos] = p;
    }
    __syncthreads();
    for (int i = threadIdx.x; i < len; i += T) sorted[e0 + i] = ssort[i];
}

// ---- u[i][j] = dinv[i] * sum_k x[i][k]*W1[k][j]  (bf16 out) ----
// R18: 4 outputs per thread. lane = (row r: tid>>2) x (jq: tid&3 -> 4 ch).
#define XR 64
#define XPAD 132
__global__ void xw1_kernel(const float* __restrict__ x, const float* __restrict__ W1,
                           const float* __restrict__ dinv, bf16* __restrict__ u, int n) {
    __shared__ float sW1[F_IN * H];        // 8 KB, [k*16 + j]
    __shared__ float sx[XR * XPAD];        // 33.8 KB
    for (int t = threadIdx.x; t < F_IN * H; t += 256) sW1[t] = W1[t];

    int basei = blockIdx.x * XR;
    for (int idx = threadIdx.x; idx < XR * 32; idx += 256) {
        int r = idx >> 5;                  // 0..63
        int kk = (idx & 31) << 2;          // 0,4,...,124
        int row = basei + r;
        float4 v = make_float4(0.f, 0.f, 0.f, 0.f);
        if (row < n) v = *(const float4*)(x + (size_t)row * F_IN + kk);
        *(float4*)(sx + r * XPAD + kk) = v;
    }
    __syncthreads();

    int r = threadIdx.x >> 2;              // 0..63
    int jq = (threadIdx.x & 3) << 2;       // 0,4,8,12
    int row = basei + r;
    if (row >= n) return;

    const float* xr = sx + r * XPAD;
    float a0 = 0.f, a1 = 0.f, a2 = 0.f, a3 = 0.f;
#pragma unroll 16
    for (int k = 0; k < F_IN; k++) {
        float xk = xr[k];
        float4 w = *(const float4*)(sW1 + k * H + jq);
        a0 += xk * w.x; a1 += xk * w.y; a2 += xk * w.z; a3 += xk * w.w;
    }
    float di = dinv[row];
    bf16 b0 = __float2bfloat16(di * a0);
    bf16 b1 = __float2bfloat16(di * a1);
    bf16 b2 = __float2bfloat16(di * a2);
    bf16 b3 = __float2bfloat16(di * a3);
    ushort4 pk = make_ushort4(*(unsigned short*)&b0, *(unsigned short*)&b1,
                              *(unsigned short*)&b2, *(unsigned short*)&b3);
    *(ushort4*)((unsigned short*)u + (size_t)row * H + jq) = pk;
}

// ================= pipelined gather core (shared by both layers) =============
// R17 lane layout: b0 = j8 (channel octet: 8 bf16 = uint4 = 16B),
// b1 = p (node parity: 2 nodes per wave-iteration), b2..b5 = g (slot 0..15).
// Depth-2 pipeline (R13 shape): prefetch sorted for pair t+1 while consuming
// uv for pair t; uv for t+1 issued after the consume.
#define GATHER_TILE(UVPTR)                                                      \
    int lane = threadIdx.x & 63;                                                \
    int wave = threadIdx.x >> 6;                                                \
    int j8 = lane & 1, pp = (lane >> 1) & 1, g = lane >> 2;                     \
    int nodeBase = blockIdx.x * NPBLK + wave * NPW;                             \
    int r0c = 0, r1c = 0;                                                       \
    unsigned svc[PFD]; uint4 uvc[PFD];                                          \
    {   int node = nodeBase + pp;                                               \
        if (node < N) { int2 rp = rowpair[node]; r0c = rp.x; r1c = rp.y; }      \
        _Pragma("unroll")                                                       \
        for (int m = 0; m < PFD; m++) {                                         \
            int k = r0c + g + 16 * m;                                           \
            if (k < r1c) svc[m] = sorted[k];                                    \
        }                                                                       \
        _Pragma("unroll")                                                       \
        for (int m = 0; m < PFD; m++) {                                         \
            int k = r0c + g + 16 * m;                                           \
            if (k < r1c) uvc[m] = UVPTR[(size_t)(svc[m] & 0x1FFFF) * 2 + j8];   \
        }                                                                       \
    }                                                                           \
    for (int t = 0; t < NPW / 2; t++) {                                         \
        int r0n = 0, r1n = 0;                                                   \
        unsigned svn[PFD];                                                      \
        if (t < NPW / 2 - 1) {                                                  \
            int nn = nodeBase + 2 * (t + 1) + pp;                               \
            if (nn < N) { int2 rp = rowpair[nn]; r0n = rp.x; r1n = rp.y; }      \
            _Pragma("unroll")                                                   \
            for (int m = 0; m < PFD; m++) {                                     \
                int k = r0n + g + 16 * m;                                       \
                if (k < r1n) svn[m] = sorted[k];                                \
            }                                                                   \
        }                                                                       \
        float a0=0.f,a1=0.f,a2=0.f,a3=0.f,a4=0.f,a5=0.f,a6=0.f,a7=0.f;          \
        _Pragma("unroll")                                                       \
        for (int m = 0; m < PFD; m++) {                                         \
            int k = r0c + g + 16 * m;                                           \
            if (k < r1c) {                                                      \
                a0 += bflo(uvc[m].x); a1 += bfhi(uvc[m].x);                     \
                a2 += bflo(uvc[m].y); a3 += bfhi(uvc[m].y);                     \
                a4 += bflo(uvc[m].z); a5 += bfhi(uvc[m].z);                     \
                a6 += bflo(uvc[m].w); a7 += bfhi(uvc[m].w);                     \
            }                                                                   \
        }                                                                       \
        for (int k = r0c + g + 16 * PFD; k < r1c; k += 16) {                    \
            uint4 va = UVPTR[(size_t)(sorted[k] & 0x1FFFF) * 2 + j8];           \
            a0 += bflo(va.x); a1 += bfhi(va.x);                                 \
            a2 += bflo(va.y); a3 += bfhi(va.y);                                 \
            a4 += bflo(va.z); a5 += bfhi(va.z);                                 \
            a6 += bflo(va.w); a7 += bfhi(va.w);                                 \
        }                                                                       \
        _Pragma("unroll")                                                       \
        for (int off = 4; off <= 32; off <<= 1) {                               \
            a0 += __shfl_xor(a0, off); a1 += __shfl_xor(a1, off);               \
            a2 += __shfl_xor(a2, off); a3 += __shfl_xor(a3, off);               \
            a4 += __shfl_xor(a4, off); a5 += __shfl_xor(a5, off);               \
            a6 += __shfl_xor(a6, off); a7 += __shfl_xor(a7, off);               \
        }                                                                       \
        if (g == 0) {                                                           \
            float* tp = &tile[(wave * NPW + 2 * t + pp) * 16 + 8 * j8];         \
            tp[0]=a0; tp[1]=a1; tp[2]=a2; tp[3]=a3;                             \
            tp[4]=a4; tp[5]=a5; tp[6]=a6; tp[7]=a7;                             \
        }                                                                       \
        if (t < NPW / 2 - 1) {                                                  \
            r0c = r0n; r1c = r1n;                                               \
            _Pragma("unroll")                                                   \
            for (int m = 0; m < PFD; m++) {                                     \
                int k = r0n + g + 16 * m;                                       \
                svc[m] = svn[m];                                                \
                if (k < r1n) uvc[m] = UVPTR[(size_t)(svn[m] & 0x1FFFF) * 2 + j8]; \
            }                                                                   \
        }                                                                       \
    }

// ---- layer-1 gather + finalize ----
__global__ void gatherfin1_kernel(const unsigned* __restrict__ sorted, const int2* __restrict__ rowpair,
                                  const bf16* __restrict__ u, const float* __restrict__ dinv,
                                  const float* __restrict__ b1, const float* __restrict__ W2,
                                  bf16* __restrict__ u2, int N) {
    __shared__ float tile[NPBLK * 16];
    __shared__ float sW2[256];
    __shared__ float sb1[16];
    sW2[threadIdx.x] = W2[threadIdx.x];
    if (threadIdx.x < 16) sb1[threadIdx.x] = b1[threadIdx.x];

    const uint4* uvp = (const uint4*)u;   // [node*2 + j8] channel octets
    GATHER_TILE(uvp)
    __syncthreads();

    int jj = threadIdx.x & 15;
    {
        int rl = threadIdx.x >> 4;                          // 0..15
        int node = blockIdx.x * NPBLK + rl;
        float h = 0.f, di = 0.f;
        if (node < N) {
            di = dinv[node];
            h = di * (tile[rl * 16 + jj] + __bfloat162float(u[(size_t)node * H + jj])) + sb1[jj];
            h = fmaxf(h, 0.f);
        }
        float acc2 = 0.f;
#pragma unroll
        for (int kk = 0; kk < 16; kk++) {
            float hk = __shfl(h, kk, 16);
            acc2 += hk * sW2[kk * 16 + jj];
        }
        if (node < N) u2[(size_t)node * H + jj] = __float2bfloat16(di * acc2);
    }
}

// ---- layer-2 gather + finalize: log_softmax -> out (f32) ----
__global__ void gatherfin2_kernel(const unsigned* __restrict__ sorted, const int2* __restrict__ rowpair,
                                  const bf16* __restrict__ u2, const float* __restrict__ dinv,
                                  const float* __restrict__ b2, float* __restrict__ out, int N) {
    __shared__ float tile[NPBLK * 16];
    __shared__ float sb2[16];
    if (threadIdx.x < 16) sb2[threadIdx.x] = b2[threadIdx.x];

    const uint4* uvp = (const uint4*)u2;
    GATHER_TILE(uvp)
    __syncthreads();

    int jj = threadIdx.x & 15;
    {
        int rl = threadIdx.x >> 4;                          // 0..15
        int node = blockIdx.x * NPBLK + rl;
        if (node < N) {
            float di = dinv[node];
            float v = di * (tile[rl * 16 + jj] + __bfloat162float(u2[(size_t)node * H + jj])) + sb2[jj];

            float m = v;
#pragma unroll
            for (int off = 8; off >= 1; off >>= 1) m = fmaxf(m, __shfl_xor(m, off, 16));
            float ex = __expf(v - m);
            float s = ex;
#pragma unroll
            for (int off = 8; off >= 1; off >>= 1) s += __shfl_xor(s, off, 16);

            out[(size_t)node * H + jj] = v - m - __logf(s);
        }
    }
}

extern "C" void kernel_launch(void* const* d_in, const int* in_sizes, int n_in,
                              void* d_out, int out_size, void* d_ws, size_t ws_size,
                              hipStream_t stream) {
    const float* x = (const float*)d_in[0];
    const int* edge_index = (const int*)d_in[1];
    const float* W1 = (const float*)d_in[2];
    const float* b1 = (const float*)d_in[3];
    const float* W2 = (const float*)d_in[4];
    const float* b2 = (const float*)d_in[5];
    float* out = (float*)d_out;

    const int N = in_sizes[0] / F_IN;        // 100000
    const int E = in_sizes[1] / 2;           // 3200000
    const int* src = edge_index;
    const int* dst = edge_index + E;
    const int NB = (N + NPB - 1) / NPB;      // 782

    // ws (4B units): dinv[N] | u[N*H/2] | u2[N*H/2] | packed[NB<<CAPB] |
    //                sorted[NB<<CAPB] | cursor[MAX_NB] | rowpair[2N]
    float* dinv = (float*)d_ws;
    bf16* u = (bf16*)(dinv + N);
    bf16* u2 = (bf16*)((unsigned*)u + (size_t)N * H / 2);
    unsigned* packed = (unsigned*)((unsigned*)u2 + (size_t)N * H / 2);
    unsigned* sorted = packed + ((size_t)MAX_NB << CAPB);
    int* cursor = (int*)(sorted + ((size_t)MAX_NB << CAPB));
    int2* rowpair = (int2*)(cursor + MAX_NB);

    init_kernel<<<1, 1024, 0, stream>>>(cursor, NB);
    binR_kernel<<<NBLK, BINT, 0, stream>>>(src, dst, cursor, packed, E, NB);
    sortcsr_kernel<<<NB, 512, 0, stream>>>(packed, cursor, sorted, rowpair, dinv, N);

    xw1_kernel<<<(N + XR - 1) / XR, 256, 0, stream>>>(x, W1, dinv, u, N);
    gatherfin1_kernel<<<(N + NPBLK - 1) / NPBLK, 256, 0, stream>>>(sorted, rowpair, u, dinv, b1, W2, u2, N);
    gatherfin2_kernel<<<(N + NPBLK - 1) / NPBLK, 256, 0, stream>>>(sorted, rowpair, u2, dinv, b2, out, N);
}

// Round 13
// 216.434 us; speedup vs baseline: 1.0822x; 1.0105x over previous
//
#include <hip/hip_runtime.h>
#include <hip/hip_bf16.h>
#include <math.h>

// N = 100000, E = 3.2M, F_in = 128, H = C = 16. int inputs arrive as int32.
//
// out[d] = dinv[d]*(sum_{s->d} u[s] + u[d]) + b,  u = dinv .* (h @ W).
// R3/R20: global per-edge atomics unusable. R21: LDS f32 atomicAdd gather
//     dead (CAS semantics). R19 coop fusion dead. R23 per-XCD sub-regions
//     regressed.
// R18 221.8 / R22 222.7 / R24 221.8 (binR multisplit fixed 4-7x write-amp)
// R25 WIN 218.7: NPW 8 -> 4 (25K waves, 3x oversub). Budget: ~82us harness
//     fills (untouchable) + gathers ~66 + binR ~30 + sortcsr ~20 + xw1 ~9.
// R26: ONE-PASS binR. Old: hist pass reads dst (12.8MB), placement pass
//     re-reads src+dst (25.6MB). New: single global read pass stores packed
//     val -> LDS scratch[12544] + bucket -> u16 bkt[12544] (sequential, no
//     atomics) while computing hist; placement pass runs from LDS. Deletes
//     12.8MB global + one latency pass. LDS 136KB/block (grid=256=1/CU, no
//     occupancy change; gfx950 allows up to 160KB).

#define F_IN 128
#define H 16
#define NPB 128            // nodes per bucket
#define MAX_NB 800         // max buckets (N <= 102400)
#define NBLK 256           // binning blocks (edge-range partition)
#define BINT 1024          // binning threads per block
#define CAPB 13            // log2 bucket capacity (8192)
#define LDSE 12544         // LDS edge buffer (>= ceil(E/NBLK) = 12500)
#define SMAX 4864          // LDS sort clamp (mean 4096, +12 sigma)
#define PFD 3              // prefetch depth: 16 slots * 3 = 48 edges/node
#define NPW 4              // nodes per wave
#define NPBLK 16           // nodes per block = 4 waves * NPW

typedef __hip_bfloat16 bf16;

__device__ __forceinline__ float bflo(unsigned v) { return __uint_as_float(v << 16); }
__device__ __forceinline__ float bfhi(unsigned v) { return __uint_as_float(v & 0xffff0000u); }

// XCD round-robin: adjacent logical edge-ranges land on the same XCD
__device__ __forceinline__ int swz(int p) { return (p & 7) * 32 + (p >> 3); }

// ---- prep 0: cursor[b] = b<<CAPB ----
__global__ void init_kernel(int* __restrict__ cursor, int NB) {
    int i = threadIdx.x;
    if (i < NB) cursor[i] = i << CAPB;
}

// ---- prep 1: ONE-PASS hist+stash -> scan -> LDS multisplit -> writeout ----
// packed value = (dst&127)<<17 | src
__global__ void __launch_bounds__(BINT)
binR_kernel(const int* __restrict__ src, const int* __restrict__ dst,
            int* __restrict__ cursor, unsigned* __restrict__ packed,
            int E, int NB) {
    __shared__ unsigned scratch[LDSE];       // 50.2 KB: packed vals, arrival order
    __shared__ unsigned short bkt[LDSE];     // 25.1 KB: bucket id per edge
    __shared__ unsigned ssort[LDSE];         // 50.2 KB: bucket-sorted vals
    __shared__ int h[MAX_NB];                // hist -> placement cursor
    __shared__ int ls[1025];                 // exclusive scan (local run starts)
    __shared__ int gb[MAX_NB];               // global reserved base per bucket
    int b = swz(blockIdx.x);
    long long e0 = (long long)E * b / NBLK;
    long long e1 = (long long)E * (b + 1) / NBLK;
    int len = (int)(e1 - e0);
    int t = threadIdx.x;

    for (int i = t; i < NB; i += BINT) h[i] = 0;
    __syncthreads();

    if (len <= LDSE) {
        // phase A: single global read; stash val+bucket in LDS, build hist
        for (int k = t; k < len; k += BINT) {
            long long e = e0 + k;
            int d = dst[e];
            scratch[k] = (unsigned)src[e] | ((unsigned)(d & 127) << 17);
            bkt[k] = (unsigned short)(d >> 7);
            atomicAdd(&h[d >> 7], 1);
        }
        __syncthreads();

        // phase B: reserve global runs + block-local exclusive scan
        int hv = (t < NB) ? h[t] : 0;
        if (t < NB) gb[t] = atomicAdd(&cursor[t], hv);
        ls[t] = hv;
        __syncthreads();
        for (int off = 1; off < 1024; off <<= 1) {
            int w = (t >= off) ? ls[t - off] : 0;
            __syncthreads();
            ls[t] += w;
            __syncthreads();
        }
        int excl = ls[t] - hv;
        __syncthreads();
        ls[t] = excl;
        if (t == 1023) ls[1024] = excl + hv;
        __syncthreads();

        // phase C: placement from LDS (no global re-read)
        if (t < NB) h[t] = ls[t];
        __syncthreads();
        for (int k = t; k < len; k += BINT) {
            int bk = bkt[k];
            int p = atomicAdd(&h[bk], 1);
            ssort[p] = scratch[k];
        }
        __syncthreads();

        // phase D: writeout per-bucket runs (coalesced)
        int wave = t >> 6, lane = t & 63;
        for (int bk = wave; bk < NB; bk += BINT / 64) {
            int s0 = ls[bk];
            int s1 = ls[bk + 1];
            int g0 = gb[bk];
            for (int i = s0 + lane; i < s1; i += 64)
                packed[g0 + (i - s0)] = ssort[i];
        }
    } else {
        // fallback (never hit for E=3.2M): two-pass direct scatter (R22)
        for (long long e = e0 + t; e < e1; e += BINT)
            atomicAdd(&h[dst[e] >> 7], 1);
        __syncthreads();
        for (int i = t; i < NB; i += BINT) {
            int c = h[i];
            int g = (c > 0) ? atomicAdd(&cursor[i], c) : 0;
            h[i] = g;
        }
        __syncthreads();
        for (long long e = e0 + t; e < e1; e += BINT) {
            int d = dst[e];
            int bk = d >> 7;
            int p = atomicAdd(&h[bk], 1);
            if (p < ((bk + 1) << CAPB))
                packed[p] = (unsigned)src[e] | ((unsigned)(d & 127) << 17);
        }
    }
}

// ---- prep 2: per-bucket LDS counting sort -> sorted[], rowpair[], dinv[] ----
__global__ void sortcsr_kernel(const unsigned* __restrict__ packed, const int* __restrict__ cursor,
                               unsigned* __restrict__ sorted, int2* __restrict__ rowpair,
                               float* __restrict__ dinv, int N) {
    __shared__ unsigned ssort[SMAX];
    __shared__ int cnt[NPB], offs[NPB], cur[NPB];
    int b = blockIdx.x;
    int e0 = b << CAPB;
    int len = cursor[b] - e0;
    if (len > SMAX) len = SMAX;
    int T = blockDim.x;

    for (int i = threadIdx.x; i < NPB; i += T) cnt[i] = 0;
    __syncthreads();
    for (int i = threadIdx.x; i < len; i += T)
        atomicAdd(&cnt[packed[e0 + i] >> 17], 1);
    __syncthreads();
    if (threadIdx.x < NPB) offs[threadIdx.x] = cnt[threadIdx.x];
    __syncthreads();
    for (int off = 1; off < NPB; off <<= 1) {
        int v = 0;
        if (threadIdx.x < NPB && threadIdx.x >= off) v = offs[threadIdx.x - off];
        __syncthreads();
        if (threadIdx.x < NPB) offs[threadIdx.x] += v;
        __syncthreads();
    }
    if (threadIdx.x < NPB) {
        int ex = offs[threadIdx.x] - cnt[threadIdx.x];
        cur[threadIdx.x] = ex;
        int node = b * NPB + threadIdx.x;
        if (node < N) {
            rowpair[node] = make_int2(e0 + ex, e0 + ex + cnt[threadIdx.x]);
            dinv[node] = rsqrtf(1.0f + (float)cnt[threadIdx.x]);
        }
    }
    __syncthreads();
    for (int i = threadIdx.x; i < len; i += T) {
        unsigned p = packed[e0 + i];
        int pos = atomicAdd(&cur[p >> 17], 1);
        ssort[pos] = p;
    }
    __syncthreads();
    for (int i = threadIdx.x; i < len; i += T) sorted[e0 + i] = ssort[i];
}

// ---- u[i][j] = dinv[i] * sum_k x[i][k]*W1[k][j]  (bf16 out) ----
// R18: 4 outputs per thread. lane = (row r: tid>>2) x (jq: tid&3 -> 4 ch).
#define XR 64
#define XPAD 132
__global__ void xw1_kernel(const float* __restrict__ x, const float* __restrict__ W1,
                           const float* __restrict__ dinv, bf16* __restrict__ u, int n) {
    __shared__ float sW1[F_IN * H];        // 8 KB, [k*16 + j]
    __shared__ float sx[XR * XPAD];        // 33.8 KB
    for (int t = threadIdx.x; t < F_IN * H; t += 256) sW1[t] = W1[t];

    int basei = blockIdx.x * XR;
    for (int idx = threadIdx.x; idx < XR * 32; idx += 256) {
        int r = idx >> 5;                  // 0..63
        int kk = (idx & 31) << 2;          // 0,4,...,124
        int row = basei + r;
        float4 v = make_float4(0.f, 0.f, 0.f, 0.f);
        if (row < n) v = *(const float4*)(x + (size_t)row * F_IN + kk);
        *(float4*)(sx + r * XPAD + kk) = v;
    }
    __syncthreads();

    int r = threadIdx.x >> 2;              // 0..63
    int jq = (threadIdx.x & 3) << 2;       // 0,4,8,12
    int row = basei + r;
    if (row >= n) return;

    const float* xr = sx + r * XPAD;
    float a0 = 0.f, a1 = 0.f, a2 = 0.f, a3 = 0.f;
#pragma unroll 16
    for (int k = 0; k < F_IN; k++) {
        float xk = xr[k];
        float4 w = *(const float4*)(sW1 + k * H + jq);
        a0 += xk * w.x; a1 += xk * w.y; a2 += xk * w.z; a3 += xk * w.w;
    }
    float di = dinv[row];
    bf16 b0 = __float2bfloat16(di * a0);
    bf16 b1 = __float2bfloat16(di * a1);
    bf16 b2 = __float2bfloat16(di * a2);
    bf16 b3 = __float2bfloat16(di * a3);
    ushort4 pk = make_ushort4(*(unsigned short*)&b0, *(unsigned short*)&b1,
                              *(unsigned short*)&b2, *(unsigned short*)&b3);
    *(ushort4*)((unsigned short*)u + (size_t)row * H + jq) = pk;
}

// ================= pipelined gather core (shared by both layers) =============
// R17 lane layout: b0 = j8 (channel octet: 8 bf16 = uint4 = 16B),
// b1 = p (node parity: 2 nodes per wave-iteration), b2..b5 = g (slot 0..15).
// Depth-2 pipeline (R13 shape): prefetch sorted for pair t+1 while consuming
// uv for pair t; uv for t+1 issued after the consume.
#define GATHER_TILE(UVPTR)                                                      \
    int lane = threadIdx.x & 63;                                                \
    int wave = threadIdx.x >> 6;                                                \
    int j8 = lane & 1, pp = (lane >> 1) & 1, g = lane >> 2;                     \
    int nodeBase = blockIdx.x * NPBLK + wave * NPW;                             \
    int r0c = 0, r1c = 0;                                                       \
    unsigned svc[PFD]; uint4 uvc[PFD];                                          \
    {   int node = nodeBase + pp;                                               \
        if (node < N) { int2 rp = rowpair[node]; r0c = rp.x; r1c = rp.y; }      \
        _Pragma("unroll")                                                       \
        for (int m = 0; m < PFD; m++) {                                         \
            int k = r0c + g + 16 * m;                                           \
            if (k < r1c) svc[m] = sorted[k];                                    \
        }                                                                       \
        _Pragma("unroll")                                                       \
        for (int m = 0; m < PFD; m++) {                                         \
            int k = r0c + g + 16 * m;                                           \
            if (k < r1c) uvc[m] = UVPTR[(size_t)(svc[m] & 0x1FFFF) * 2 + j8];   \
        }                                                                       \
    }                                                                           \
    for (int t = 0; t < NPW / 2; t++) {                                         \
        int r0n = 0, r1n = 0;                                                   \
        unsigned svn[PFD];                                                      \
        if (t < NPW / 2 - 1) {                                                  \
            int nn = nodeBase + 2 * (t + 1) + pp;                               \
            if (nn < N) { int2 rp = rowpair[nn]; r0n = rp.x; r1n = rp.y; }      \
            _Pragma("unroll")                                                   \
            for (int m = 0; m < PFD; m++) {                                     \
                int k = r0n + g + 16 * m;                                       \
                if (k < r1n) svn[m] = sorted[k];                                \
            }                                                                   \
        }                                                                       \
        float a0=0.f,a1=0.f,a2=0.f,a3=0.f,a4=0.f,a5=0.f,a6=0.f,a7=0.f;          \
        _Pragma("unroll")                                                       \
        for (int m = 0; m < PFD; m++) {                                         \
            int k = r0c + g + 16 * m;                                           \
            if (k < r1c) {                                                      \
                a0 += bflo(uvc[m].x); a1 += bfhi(uvc[m].x);                     \
                a2 += bflo(uvc[m].y); a3 += bfhi(uvc[m].y);                     \
                a4 += bflo(uvc[m].z); a5 += bfhi(uvc[m].z);                     \
                a6 += bflo(uvc[m].w); a7 += bfhi(uvc[m].w);                     \
            }                                                                   \
        }                                                                       \
        for (int k = r0c + g + 16 * PFD; k < r1c; k += 16) {                    \
            uint4 va = UVPTR[(size_t)(sorted[k] & 0x1FFFF) * 2 + j8];           \
            a0 += bflo(va.x); a1 += bfhi(va.x);                                 \
            a2 += bflo(va.y); a3 += bfhi(va.y);                                 \
            a4 += bflo(va.z); a5 += bfhi(va.z);                                 \
            a6 += bflo(va.w); a7 += bfhi(va.w);                                 \
        }                                                                       \
        _Pragma("unroll")                                                       \
        for (int off = 4; off <= 32; off <<= 1) {                               \
            a0 += __shfl_xor(a0, off); a1 += __shfl_xor(a1, off);               \
            a2 += __shfl_xor(a2, off); a3 += __shfl_xor(a3, off);               \
            a4 += __shfl_xor(a4, off); a5 += __shfl_xor(a5, off);               \
            a6 += __shfl_xor(a6, off); a7 += __shfl_xor(a7, off);               \
        }                                                                       \
        if (g == 0) {                                                           \
            float* tp = &tile[(wave * NPW + 2 * t + pp) * 16 + 8 * j8];         \
            tp[0]=a0; tp[1]=a1; tp[2]=a2; tp[3]=a3;                             \
            tp[4]=a4; tp[5]=a5; tp[6]=a6; tp[7]=a7;                             \
        }                                                                       \
        if (t < NPW / 2 - 1) {                                                  \
            r0c = r0n; r1c = r1n;                                               \
            _Pragma("unroll")                                                   \
            for (int m = 0; m < PFD; m++) {                                     \
                int k = r0n + g + 16 * m;                                       \
                svc[m] = svn[m];                                                \
                if (k < r1n) uvc[m] = UVPTR[(size_t)(svn[m] & 0x1FFFF) * 2 + j8]; \
            }                                                                   \
        }                                                                       \
    }

// ---- layer-1 gather + finalize ----
__global__ void gatherfin1_kernel(const unsigned* __restrict__ sorted, const int2* __restrict__ rowpair,
                                  const bf16* __restrict__ u, const float* __restrict__ dinv,
                                  const float* __restrict__ b1, const float* __restrict__ W2,
                                  bf16* __restrict__ u2, int N) {
    __shared__ float tile[NPBLK * 16];
    __shared__ float sW2[256];
    __shared__ float sb1[16];
    sW2[threadIdx.x] = W2[threadIdx.x];
    if (threadIdx.x < 16) sb1[threadIdx.x] = b1[threadIdx.x];

    const uint4* uvp = (const uint4*)u;   // [node*2 + j8] channel octets
    GATHER_TILE(uvp)
    __syncthreads();

    int jj = threadIdx.x & 15;
    {
        int rl = threadIdx.x >> 4;                          // 0..15
        int node = blockIdx.x * NPBLK + rl;
        float h = 0.f, di = 0.f;
        if (node < N) {
            di = dinv[node];
            h = di * (tile[rl * 16 + jj] + __bfloat162float(u[(size_t)node * H + jj])) + sb1[jj];
            h = fmaxf(h, 0.f);
        }
        float acc2 = 0.f;
#pragma unroll
        for (int kk = 0; kk < 16; kk++) {
            float hk = __shfl(h, kk, 16);
            acc2 += hk * sW2[kk * 16 + jj];
        }
        if (node < N) u2[(size_t)node * H + jj] = __float2bfloat16(di * acc2);
    }
}

// ---- layer-2 gather + finalize: log_softmax -> out (f32) ----
__global__ void gatherfin2_kernel(const unsigned* __restrict__ sorted, const int2* __restrict__ rowpair,
                                  const bf16* __restrict__ u2, const float* __restrict__ dinv,
                                  const float* __restrict__ b2, float* __restrict__ out, int N) {
    __shared__ float tile[NPBLK * 16];
    __shared__ float sb2[16];
    if (threadIdx.x < 16) sb2[threadIdx.x] = b2[threadIdx.x];

    const uint4* uvp = (const uint4*)u2;
    GATHER_TILE(uvp)
    __syncthreads();

    int jj = threadIdx.x & 15;
    {
        int rl = threadIdx.x >> 4;                          // 0..15
        int node = blockIdx.x * NPBLK + rl;
        if (node < N) {
            float di = dinv[node];
            float v = di * (tile[rl * 16 + jj] + __bfloat162float(u2[(size_t)node * H + jj])) + sb2[jj];

            float m = v;
#pragma unroll
            for (int off = 8; off >= 1; off >>= 1) m = fmaxf(m, __shfl_xor(m, off, 16));
            float ex = __expf(v - m);
            float s = ex;
#pragma unroll
            for (int off = 8; off >= 1; off >>= 1) s += __shfl_xor(s, off, 16);

            out[(size_t)node * H + jj] = v - m - __logf(s);
        }
    }
}

extern "C" void kernel_launch(void* const* d_in, const int* in_sizes, int n_in,
                              void* d_out, int out_size, void* d_ws, size_t ws_size,
                              hipStream_t stream) {
    const float* x = (const float*)d_in[0];
    const int* edge_index = (const int*)d_in[1];
    const float* W1 = (const float*)d_in[2];
    const float* b1 = (const float*)d_in[3];
    const float* W2 = (const float*)d_in[4];
    const float* b2 = (const float*)d_in[5];
    float* out = (float*)d_out;

    const int N = in_sizes[0] / F_IN;        // 100000
    const int E = in_sizes[1] / 2;           // 3200000
    const int* src = edge_index;
    const int* dst = edge_index + E;
    const int NB = (N + NPB - 1) / NPB;      // 782

    // ws (4B units): dinv[N] | u[N*H/2] | u2[N*H/2] | packed[NB<<CAPB] |
    //                sorted[NB<<CAPB] | cursor[MAX_NB] | rowpair[2N]
    float* dinv = (float*)d_ws;
    bf16* u = (bf16*)(dinv + N);
    bf16* u2 = (bf16*)((unsigned*)u + (size_t)N * H / 2);
    unsigned* packed = (unsigned*)((unsigned*)u2 + (size_t)N * H / 2);
    unsigned* sorted = packed + ((size_t)MAX_NB << CAPB);
    int* cursor = (int*)(sorted + ((size_t)MAX_NB << CAPB));
    int2* rowpair = (int2*)(cursor + MAX_NB);

    init_kernel<<<1, 1024, 0, stream>>>(cursor, NB);
    binR_kernel<<<NBLK, BINT, 0, stream>>>(src, dst, cursor, packed, E, NB);
    sortcsr_kernel<<<NB, 512, 0, stream>>>(packed, cursor, sorted, rowpair, dinv, N);

    xw1_kernel<<<(N + XR - 1) / XR, 256, 0, stream>>>(x, W1, dinv, u, N);
    gatherfin1_kernel<<<(N + NPBLK - 1) / NPBLK, 256, 0, stream>>>(sorted, rowpair, u, dinv, b1, W2, u2, N);
    gatherfin2_kernel<<<(N + NPBLK - 1) / NPBLK, 256, 0, stream>>>(sorted, rowpair, u2, dinv, b2, out, N);
}